// Round 1
// baseline (342.847 us; speedup 1.0000x reference)
//
#include <hip/hip_runtime.h>

typedef unsigned short u16;
typedef __bf16 bf16x8 __attribute__((ext_vector_type(8)));
typedef float f32x4 __attribute__((ext_vector_type(4)));

#define B_SZ 256
#define T_SZ 256
#define C_EMB 384
#define NHEAD 6
#define DHEAD 64
#define N3 1152
#define M_TOT 65536
#define BHTD 25165824   // B*H*T*D elements per tensor
#define SCALE 0.05103103630798287f  // 384^-0.5

__device__ __forceinline__ u16 f2bf(float f) {
  unsigned u = __float_as_uint(f);
  u += 0x7FFFu + ((u >> 16) & 1u);   // RNE
  return (u16)(u >> 16);
}

__device__ __forceinline__ void gload_lds16(const void* g, void* l) {
  __builtin_amdgcn_global_load_lds((const __attribute__((address_space(1))) void*)g,
                                   (__attribute__((address_space(3))) void*)l, 16, 0, 0);
}

// ---------------- weight prep: bf16 + transpose to [n][k] ----------------
__global__ __launch_bounds__(256) void prep_weights(
    const float* __restrict__ wk, const float* __restrict__ wq,
    const float* __restrict__ wv, const float* __restrict__ wproj,
    u16* __restrict__ wqkvt, u16* __restrict__ wprojt) {
  int i = blockIdx.x * 256 + threadIdx.x;
  if (i < N3 * C_EMB) {
    int n = i / C_EMB, c = i - n * C_EMB;
    int tensor = n >= 768 ? 2 : (n >= 384 ? 1 : 0);
    int r = n - tensor * 384;
    int h = r >> 6, d = r & 63;
    const float* w = tensor == 0 ? wk : (tensor == 1 ? wq : wv);
    wqkvt[i] = f2bf(w[(h * C_EMB + c) * DHEAD + d]);
  } else {
    int ii = i - N3 * C_EMB;
    if (ii < C_EMB * C_EMB) {
      int n = ii / C_EMB, c = ii - n * C_EMB;
      wprojt[ii] = f2bf(wproj[c * C_EMB + n]);  // transpose
    }
  }
}

// ---------------- QKV GEMM: [65536,384] x [384,1152] -> k/q/v [b][h][t][d] bf16
__global__ __launch_bounds__(256) void qkv_gemm(const float* __restrict__ x,
                                                const u16* __restrict__ wt,
                                                u16* __restrict__ kqv) {
  __shared__ __align__(16) u16 lA[128 * 64];
  __shared__ __align__(16) u16 lB[128 * 64];
  const int tid = threadIdx.x;
  const int lane = tid & 63, w = tid >> 6;
  const int n0 = blockIdx.x * 128, m0 = blockIdx.y * 128;
  const int wr = w >> 1, wc = w & 1;
  f32x4 acc[4][4] = {};
  for (int kt = 0; kt < 6; ++kt) {
    const int k0 = kt * 64;
    __syncthreads();
    // stage B (bf16 weights) via global_load_lds, pre-swizzled source (rule #21)
#pragma unroll
    for (int it = 0; it < 4; ++it) {
      int ub = it * 256 + w * 64;
      int u = ub + lane;
      int row = u >> 3, cu = u & 7;
      gload_lds16(wt + (size_t)(n0 + row) * C_EMB + k0 + ((cu ^ (row & 7)) << 3),
                  lB + ub * 8);
    }
    // stage A (fp32 x -> bf16), swizzled LDS write
#pragma unroll
    for (int it = 0; it < 4; ++it) {
      int u = it * 256 + tid;
      int row = u >> 3, cu = u & 7;
      const float* s = x + (size_t)(m0 + row) * C_EMB + k0 + cu * 8;
      float4 f0 = *(const float4*)s;
      float4 f1 = *(const float4*)(s + 4);
      uint4 p;
      p.x = (unsigned)f2bf(f0.x) | ((unsigned)f2bf(f0.y) << 16);
      p.y = (unsigned)f2bf(f0.z) | ((unsigned)f2bf(f0.w) << 16);
      p.z = (unsigned)f2bf(f1.x) | ((unsigned)f2bf(f1.y) << 16);
      p.w = (unsigned)f2bf(f1.z) | ((unsigned)f2bf(f1.w) << 16);
      *(uint4*)((char*)lA + row * 128 + ((cu ^ (row & 7)) << 4)) = p;
    }
    __syncthreads();
    bf16x8 af[4][2], bfr[4][2];
#pragma unroll
    for (int mi = 0; mi < 4; ++mi) {
      int row = wr * 64 + mi * 16 + (lane & 15);
#pragma unroll
      for (int kk = 0; kk < 2; ++kk) {
        int cu = kk * 4 + (lane >> 4);
        af[mi][kk] = *(const bf16x8*)((const char*)lA + row * 128 + ((cu ^ (row & 7)) << 4));
      }
    }
#pragma unroll
    for (int ni = 0; ni < 4; ++ni) {
      int row = wc * 64 + ni * 16 + (lane & 15);
#pragma unroll
      for (int kk = 0; kk < 2; ++kk) {
        int cu = kk * 4 + (lane >> 4);
        bfr[ni][kk] = *(const bf16x8*)((const char*)lB + row * 128 + ((cu ^ (row & 7)) << 4));
      }
    }
#pragma unroll
    for (int kk = 0; kk < 2; ++kk)
#pragma unroll
      for (int mi = 0; mi < 4; ++mi)
#pragma unroll
        for (int ni = 0; ni < 4; ++ni)
          acc[mi][ni] = __builtin_amdgcn_mfma_f32_16x16x32_bf16(
              af[mi][kk], bfr[ni][kk], acc[mi][ni], 0, 0, 0);
  }
  // epilogue: scatter to k/q/v [tensor][b][h][t][d] bf16
#pragma unroll
  for (int ni = 0; ni < 4; ++ni) {
    int gn = n0 + wc * 64 + ni * 16 + (lane & 15);
    int tensor = gn >= 768 ? 2 : (gn >= 384 ? 1 : 0);
    int h = (gn - tensor * 384) >> 6;
    int d = gn & 63;
#pragma unroll
    for (int mi = 0; mi < 4; ++mi) {
      int gm0 = m0 + wr * 64 + mi * 16 + ((lane >> 4) << 2);
#pragma unroll
      for (int r = 0; r < 4; ++r) {
        int m = gm0 + r;
        int b = m >> 8, t = m & 255;
        kqv[(size_t)tensor * BHTD + ((((b * NHEAD + h) << 8) + t) << 6) + d] =
            f2bf(acc[mi][ni][r]);
      }
    }
  }
}

// ---------------- causal flash attention, S[t,s] = K[t]·Q[s] / sqrt(384) ----
__global__ __launch_bounds__(256) void attn_kernel(const u16* __restrict__ kqv,
                                                   u16* __restrict__ attnb) {
  __shared__ __align__(16) u16 lK[64 * 64];
  __shared__ __align__(16) u16 lQ[64 * 64];
  __shared__ __align__(16) u16 lVt[64 * 64];
  __shared__ __align__(16) u16 lP[4 * 16 * 64];
  const int tid = threadIdx.x;
  const int lane = tid & 63, w = tid >> 6;
  const int t0 = blockIdx.x * 64;
  const int bh = blockIdx.y;
  const u16* Kb = kqv + (size_t)bh * (T_SZ * DHEAD);
  const u16* Qb = kqv + (size_t)BHTD + (size_t)bh * (T_SZ * DHEAD);
  const u16* Vb = kqv + 2 * (size_t)BHTD + (size_t)bh * (T_SZ * DHEAD);
  // stage K tile (64 rows t0..t0+63), swizzled via pre-swizzled source
#pragma unroll
  for (int it = 0; it < 2; ++it) {
    int ub = it * 256 + w * 64;
    int u = ub + lane;
    int row = u >> 3, cu = u & 7;
    gload_lds16(Kb + (t0 + row) * DHEAD + ((cu ^ (row & 7)) << 3), lK + ub * 8);
  }
  f32x4 oacc[4] = {};
  float mrow[4] = {-1e30f, -1e30f, -1e30f, -1e30f};
  float lrow[4] = {0.f, 0.f, 0.f, 0.f};
  const int nst = (t0 >> 6) + 1;
  for (int si = 0; si < nst; ++si) {
    const int s0 = si << 6;
    __syncthreads();
#pragma unroll
    for (int it = 0; it < 2; ++it) {
      int ub = it * 256 + w * 64;
      int u = ub + lane;
      int row = u >> 3, cu = u & 7;
      gload_lds16(Qb + (s0 + row) * DHEAD + ((cu ^ (row & 7)) << 3), lQ + ub * 8);
    }
    // V transposed into LDS [d][s], swizzled
#pragma unroll
    for (int it = 0; it < 2; ++it) {
      int u = it * 256 + tid;
      int srow = u >> 3, d0 = (u & 7) << 3;
      uint4 vv = *(const uint4*)(Vb + (s0 + srow) * DHEAD + d0);
      const u16* pv = (const u16*)&vv;
#pragma unroll
      for (int j = 0; j < 8; ++j) {
        int dd = d0 + j;
        int byte = dd * 128 + srow * 2;
        byte ^= (dd & 7) << 4;
        *(u16*)((char*)lVt + byte) = pv[j];
      }
    }
    __syncthreads();
    // S = K Q^T  (wave w owns t rows w*16..w*16+15, all 64 s cols)
    bf16x8 af[2];
    {
      int row = w * 16 + (lane & 15);
#pragma unroll
      for (int kk = 0; kk < 2; ++kk) {
        int cu = kk * 4 + (lane >> 4);
        af[kk] = *(const bf16x8*)((const char*)lK + row * 128 + ((cu ^ (row & 7)) << 4));
      }
    }
    f32x4 sacc[4] = {};
#pragma unroll
    for (int ni = 0; ni < 4; ++ni) {
      int row = ni * 16 + (lane & 15);
#pragma unroll
      for (int kk = 0; kk < 2; ++kk) {
        int cu = kk * 4 + (lane >> 4);
        bf16x8 bq = *(const bf16x8*)((const char*)lQ + row * 128 + ((cu ^ (row & 7)) << 4));
        sacc[ni] = __builtin_amdgcn_mfma_f32_16x16x32_bf16(af[kk], bq, sacc[ni], 0, 0, 0);
      }
    }
    // mask + online softmax (rows live on 16-lane groups)
    const int tg0 = t0 + w * 16 + ((lane >> 4) << 2);
    float pm[4][4];
    float rmax[4] = {-1e30f, -1e30f, -1e30f, -1e30f};
#pragma unroll
    for (int ni = 0; ni < 4; ++ni) {
      int sg = s0 + ni * 16 + (lane & 15);
#pragma unroll
      for (int r = 0; r < 4; ++r) {
        float vv = sacc[ni][r] * SCALE;
        if (sg > tg0 + r) vv = -1e30f;
        pm[ni][r] = vv;
        rmax[r] = fmaxf(rmax[r], vv);
      }
    }
#pragma unroll
    for (int r = 0; r < 4; ++r) {
#pragma unroll
      for (int off = 1; off < 16; off <<= 1)
        rmax[r] = fmaxf(rmax[r], __shfl_xor(rmax[r], off));
    }
    float alpha[4], rsum[4];
#pragma unroll
    for (int r = 0; r < 4; ++r) {
      float mnew = fmaxf(mrow[r], rmax[r]);
      alpha[r] = __expf(mrow[r] - mnew);
      mrow[r] = mnew;
      rsum[r] = 0.f;
    }
#pragma unroll
    for (int ni = 0; ni < 4; ++ni)
#pragma unroll
      for (int r = 0; r < 4; ++r) {
        float p = __expf(pm[ni][r] - mrow[r]);
        pm[ni][r] = p;
        rsum[r] += p;
      }
#pragma unroll
    for (int r = 0; r < 4; ++r) {
#pragma unroll
      for (int off = 1; off < 16; off <<= 1)
        rsum[r] += __shfl_xor(rsum[r], off);
      lrow[r] = lrow[r] * alpha[r] + rsum[r];
    }
#pragma unroll
    for (int nd = 0; nd < 4; ++nd)
#pragma unroll
      for (int r = 0; r < 4; ++r) oacc[nd][r] *= alpha[r];
    // P -> per-wave LDS (bf16, swizzled); same-wave write->read, no barrier needed
    u16* lPw = lP + w * 1024;
#pragma unroll
    for (int ni = 0; ni < 4; ++ni) {
      int scol = ni * 16 + (lane & 15);
#pragma unroll
      for (int r = 0; r < 4; ++r) {
        int trow = ((lane >> 4) << 2) + r;
        int byte = trow * 128 + scol * 2;
        byte ^= (trow & 7) << 4;
        *(u16*)((char*)lPw + byte) = f2bf(pm[ni][r]);
      }
    }
    // O += P @ V
    bf16x8 pa[2];
    {
      int trow = lane & 15;
#pragma unroll
      for (int kk = 0; kk < 2; ++kk) {
        int cu = kk * 4 + (lane >> 4);
        pa[kk] = *(const bf16x8*)((const char*)lPw + trow * 128 + ((cu ^ (trow & 7)) << 4));
      }
    }
#pragma unroll
    for (int nd = 0; nd < 4; ++nd) {
      int drow = nd * 16 + (lane & 15);
#pragma unroll
      for (int kk = 0; kk < 2; ++kk) {
        int cu = kk * 4 + (lane >> 4);
        bf16x8 vb = *(const bf16x8*)((const char*)lVt + drow * 128 + ((cu ^ (drow & 7)) << 4));
        oacc[nd] = __builtin_amdgcn_mfma_f32_16x16x32_bf16(pa[kk], vb, oacc[nd], 0, 0, 0);
      }
    }
  }
  // epilogue: attn [b][t][h*64+d] bf16
  const int b = bh / NHEAD, h = bh - (bh / NHEAD) * NHEAD;
#pragma unroll
  for (int r = 0; r < 4; ++r) {
    int t = t0 + w * 16 + ((lane >> 4) << 2) + r;
    float inv = 1.0f / lrow[r];
#pragma unroll
    for (int nd = 0; nd < 4; ++nd) {
      int col = h * 64 + nd * 16 + (lane & 15);
      attnb[((size_t)(b * T_SZ + t)) * C_EMB + col] = f2bf(oacc[nd][r] * inv);
    }
  }
}

// ---------------- out projection: [65536,384] x [384,384] + bias -> fp32 ----
__global__ __launch_bounds__(256) void out_gemm(const u16* __restrict__ a,
                                                const u16* __restrict__ wt,
                                                const float* __restrict__ bias,
                                                float* __restrict__ out) {
  __shared__ __align__(16) u16 lA[128 * 64];
  __shared__ __align__(16) u16 lB[128 * 64];
  const int tid = threadIdx.x;
  const int lane = tid & 63, w = tid >> 6;
  const int n0 = blockIdx.x * 128, m0 = blockIdx.y * 128;
  const int wr = w >> 1, wc = w & 1;
  f32x4 acc[4][4] = {};
  for (int kt = 0; kt < 6; ++kt) {
    const int k0 = kt * 64;
    __syncthreads();
#pragma unroll
    for (int it = 0; it < 4; ++it) {
      int ub = it * 256 + w * 64;
      int u = ub + lane;
      int row = u >> 3, cu = u & 7;
      gload_lds16(a + (size_t)(m0 + row) * C_EMB + k0 + ((cu ^ (row & 7)) << 3),
                  lA + ub * 8);
      gload_lds16(wt + (size_t)(n0 + row) * C_EMB + k0 + ((cu ^ (row & 7)) << 3),
                  lB + ub * 8);
    }
    __syncthreads();
    bf16x8 af[4][2], bfr[4][2];
#pragma unroll
    for (int mi = 0; mi < 4; ++mi) {
      int row = wr * 64 + mi * 16 + (lane & 15);
#pragma unroll
      for (int kk = 0; kk < 2; ++kk) {
        int cu = kk * 4 + (lane >> 4);
        af[mi][kk] = *(const bf16x8*)((const char*)lA + row * 128 + ((cu ^ (row & 7)) << 4));
      }
    }
#pragma unroll
    for (int ni = 0; ni < 4; ++ni) {
      int row = wc * 64 + ni * 16 + (lane & 15);
#pragma unroll
      for (int kk = 0; kk < 2; ++kk) {
        int cu = kk * 4 + (lane >> 4);
        bfr[ni][kk] = *(const bf16x8*)((const char*)lB + row * 128 + ((cu ^ (row & 7)) << 4));
      }
    }
#pragma unroll
    for (int kk = 0; kk < 2; ++kk)
#pragma unroll
      for (int mi = 0; mi < 4; ++mi)
#pragma unroll
        for (int ni = 0; ni < 4; ++ni)
          acc[mi][ni] = __builtin_amdgcn_mfma_f32_16x16x32_bf16(
              af[mi][kk], bfr[ni][kk], acc[mi][ni], 0, 0, 0);
  }
#pragma unroll
  for (int ni = 0; ni < 4; ++ni) {
    int gn = n0 + wc * 64 + ni * 16 + (lane & 15);
    float bv = bias[gn];
#pragma unroll
    for (int mi = 0; mi < 4; ++mi) {
      int gm0 = m0 + wr * 64 + mi * 16 + ((lane >> 4) << 2);
#pragma unroll
      for (int r = 0; r < 4; ++r)
        out[(size_t)(gm0 + r) * C_EMB + gn] = acc[mi][ni][r] + bv;
    }
  }
}

extern "C" void kernel_launch(void* const* d_in, const int* in_sizes, int n_in,
                              void* d_out, int out_size, void* d_ws, size_t ws_size,
                              hipStream_t stream) {
  const float* x = (const float*)d_in[0];
  const float* wk = (const float*)d_in[1];
  const float* wq = (const float*)d_in[2];
  const float* wv = (const float*)d_in[3];
  const float* wproj = (const float*)d_in[4];
  const float* bproj = (const float*)d_in[5];
  float* out = (float*)d_out;
  u16* ws = (u16*)d_ws;
  u16* kqv = ws;                               // 3 * BHTD bf16
  u16* attnb = ws + 3 * (size_t)BHTD;          // BHTD bf16
  u16* wqkvt = attnb + (size_t)BHTD;           // 1152*384
  u16* wprojt = wqkvt + (size_t)N3 * C_EMB;    // 384*384
  prep_weights<<<2304, 256, 0, stream>>>(wk, wq, wv, wproj, wqkvt, wprojt);
  qkv_gemm<<<dim3(9, 512), 256, 0, stream>>>(x, wqkvt, kqv);
  attn_kernel<<<dim3(4, 1536), 256, 0, stream>>>(kqv, attnb);
  out_gemm<<<dim3(3, 512), 256, 0, stream>>>(attnb, wprojt, bproj, out);
}

// Round 2
// 260.380 us; speedup vs baseline: 1.3167x; 1.3167x over previous
//
#include <hip/hip_runtime.h>

typedef unsigned short u16;
typedef __bf16 bf16x8 __attribute__((ext_vector_type(8)));
typedef float f32x4 __attribute__((ext_vector_type(4)));

#define B_SZ 256
#define T_SZ 256
#define C_EMB 384
#define NHEAD 6
#define DHEAD 64
#define N3 1152
#define M_TOT 65536
#define BHTD 25165824   // B*H*T*D elements per tensor
#define SCALE 0.05103103630798287f  // 384^-0.5

__device__ __forceinline__ u16 f2bf(float f) {
  unsigned u = __float_as_uint(f);
  u += 0x7FFFu + ((u >> 16) & 1u);   // RNE
  return (u16)(u >> 16);
}

__device__ __forceinline__ void gload_lds16(const void* g, void* l) {
  __builtin_amdgcn_global_load_lds((const __attribute__((address_space(1))) void*)g,
                                   (__attribute__((address_space(3))) void*)l, 16, 0, 0);
}

// ---------------- weight prep: bf16 + transpose to [n][k] ----------------
__global__ __launch_bounds__(256) void prep_weights(
    const float* __restrict__ wk, const float* __restrict__ wq,
    const float* __restrict__ wv, const float* __restrict__ wproj,
    u16* __restrict__ wqkvt, u16* __restrict__ wprojt) {
  int i = blockIdx.x * 256 + threadIdx.x;
  if (i < N3 * C_EMB) {
    int n = i / C_EMB, c = i - n * C_EMB;
    int tensor = n >= 768 ? 2 : (n >= 384 ? 1 : 0);
    int r = n - tensor * 384;
    int h = r >> 6, d = r & 63;
    const float* w = tensor == 0 ? wk : (tensor == 1 ? wq : wv);
    wqkvt[i] = f2bf(w[(h * C_EMB + c) * DHEAD + d]);
  } else {
    int ii = i - N3 * C_EMB;
    if (ii < C_EMB * C_EMB) {
      int n = ii / C_EMB, c = ii - n * C_EMB;
      wprojt[ii] = f2bf(wproj[c * C_EMB + n]);  // transpose
    }
  }
}

// ---------------- x -> bf16 (8 elems/thread, coalesced 16B stores) ----------
__global__ __launch_bounds__(256) void prep_x(const float* __restrict__ x,
                                              u16* __restrict__ xb) {
  int i = blockIdx.x * 256 + threadIdx.x;   // unit of 8 floats
  float4 f0 = ((const float4*)x)[i * 2];
  float4 f1 = ((const float4*)x)[i * 2 + 1];
  uint4 p;
  p.x = (unsigned)f2bf(f0.x) | ((unsigned)f2bf(f0.y) << 16);
  p.y = (unsigned)f2bf(f0.z) | ((unsigned)f2bf(f0.w) << 16);
  p.z = (unsigned)f2bf(f1.x) | ((unsigned)f2bf(f1.y) << 16);
  p.w = (unsigned)f2bf(f1.z) | ((unsigned)f2bf(f1.w) << 16);
  ((uint4*)xb)[i] = p;
}

// ---------------- QKV GEMM: [65536,384] x [384,1152] -> k/q/v [b][h][t][d] bf16
__global__ __launch_bounds__(256) void qkv_gemm(const u16* __restrict__ xb,
                                                const u16* __restrict__ wt,
                                                u16* __restrict__ kqv) {
  __shared__ __align__(16) u16 lA[128 * 64];
  __shared__ __align__(16) u16 lB[128 * 64];
  const int tid = threadIdx.x;
  const int lane = tid & 63, w = tid >> 6;
  // T1: XCD-aware swizzle; 4608 wgs = 8 XCDs x 576; nt-fastest within chunk
  int bid = blockIdx.x;
  int nb = (bid & 7) * 576 + (bid >> 3);
  int mt = nb / 9, nt = nb - mt * 9;
  const int n0 = nt * 128, m0 = mt * 128;
  const int wr = w >> 1, wc = w & 1;
  f32x4 acc[4][4] = {};
  for (int kt = 0; kt < 6; ++kt) {
    const int k0 = kt * 64;
    __syncthreads();
    // stage A (bf16 x) + B (bf16 weights) via global_load_lds, pre-swizzled src
#pragma unroll
    for (int it = 0; it < 4; ++it) {
      int ub = it * 256 + w * 64;
      int u = ub + lane;
      int row = u >> 3, cu = u & 7;
      int koff = k0 + ((cu ^ (row & 7)) << 3);
      gload_lds16(xb + (size_t)(m0 + row) * C_EMB + koff, lA + ub * 8);
      gload_lds16(wt + (size_t)(n0 + row) * C_EMB + koff, lB + ub * 8);
    }
    __syncthreads();
    bf16x8 af[4][2], bfr[4][2];
#pragma unroll
    for (int mi = 0; mi < 4; ++mi) {
      int row = wr * 64 + mi * 16 + (lane & 15);
#pragma unroll
      for (int kk = 0; kk < 2; ++kk) {
        int cu = kk * 4 + (lane >> 4);
        af[mi][kk] = *(const bf16x8*)((const char*)lA + row * 128 + ((cu ^ (row & 7)) << 4));
      }
    }
#pragma unroll
    for (int ni = 0; ni < 4; ++ni) {
      int row = wc * 64 + ni * 16 + (lane & 15);
#pragma unroll
      for (int kk = 0; kk < 2; ++kk) {
        int cu = kk * 4 + (lane >> 4);
        bfr[ni][kk] = *(const bf16x8*)((const char*)lB + row * 128 + ((cu ^ (row & 7)) << 4));
      }
    }
#pragma unroll
    for (int kk = 0; kk < 2; ++kk)
#pragma unroll
      for (int mi = 0; mi < 4; ++mi)
#pragma unroll
        for (int ni = 0; ni < 4; ++ni)
          acc[mi][ni] = __builtin_amdgcn_mfma_f32_16x16x32_bf16(
              af[mi][kk], bfr[ni][kk], acc[mi][ni], 0, 0, 0);
  }
  // epilogue: scatter to k/q/v [tensor][b][h][t][d] bf16
#pragma unroll
  for (int ni = 0; ni < 4; ++ni) {
    int gn = n0 + wc * 64 + ni * 16 + (lane & 15);
    int tensor = gn >= 768 ? 2 : (gn >= 384 ? 1 : 0);
    int h = (gn - tensor * 384) >> 6;
    int d = gn & 63;
#pragma unroll
    for (int mi = 0; mi < 4; ++mi) {
      int gm0 = m0 + wr * 64 + mi * 16 + ((lane >> 4) << 2);
#pragma unroll
      for (int r = 0; r < 4; ++r) {
        int m = gm0 + r;
        int b = m >> 8, t = m & 255;
        kqv[(size_t)tensor * BHTD + ((((b * NHEAD + h) << 8) + t) << 6) + d] =
            f2bf(acc[mi][ni][r]);
      }
    }
  }
}

// ---------------- causal flash attention, S[t,s] = K[t]·Q[s] / sqrt(384) ----
__global__ __launch_bounds__(256) void attn_kernel(const u16* __restrict__ kqv,
                                                   u16* __restrict__ attnb) {
  __shared__ __align__(16) u16 lK[64 * 64];
  __shared__ __align__(16) u16 lQ[64 * 64];
  __shared__ __align__(16) u16 lVt[64 * 64];
  __shared__ __align__(16) u16 lP[4 * 16 * 64];
  const int tid = threadIdx.x;
  const int lane = tid & 63, w = tid >> 6;
  const int t0 = blockIdx.x * 64;
  const int bh = blockIdx.y;
  const u16* Kb = kqv + (size_t)bh * (T_SZ * DHEAD);
  const u16* Qb = kqv + (size_t)BHTD + (size_t)bh * (T_SZ * DHEAD);
  const u16* Vb = kqv + 2 * (size_t)BHTD + (size_t)bh * (T_SZ * DHEAD);
  // stage K tile (64 rows t0..t0+63), swizzled via pre-swizzled source
#pragma unroll
  for (int it = 0; it < 2; ++it) {
    int ub = it * 256 + w * 64;
    int u = ub + lane;
    int row = u >> 3, cu = u & 7;
    gload_lds16(Kb + (t0 + row) * DHEAD + ((cu ^ (row & 7)) << 3), lK + ub * 8);
  }
  f32x4 oacc[4] = {};
  float mrow[4] = {-1e30f, -1e30f, -1e30f, -1e30f};
  float lrow[4] = {0.f, 0.f, 0.f, 0.f};
  const int nst = (t0 >> 6) + 1;
  for (int si = 0; si < nst; ++si) {
    const int s0 = si << 6;
    __syncthreads();
#pragma unroll
    for (int it = 0; it < 2; ++it) {
      int ub = it * 256 + w * 64;
      int u = ub + lane;
      int row = u >> 3, cu = u & 7;
      gload_lds16(Qb + (s0 + row) * DHEAD + ((cu ^ (row & 7)) << 3), lQ + ub * 8);
    }
    // V transposed into LDS [d][s], swizzled
#pragma unroll
    for (int it = 0; it < 2; ++it) {
      int u = it * 256 + tid;
      int srow = u >> 3, d0 = (u & 7) << 3;
      uint4 vv = *(const uint4*)(Vb + (s0 + srow) * DHEAD + d0);
      const u16* pv = (const u16*)&vv;
#pragma unroll
      for (int j = 0; j < 8; ++j) {
        int dd = d0 + j;
        int byte = dd * 128 + srow * 2;
        byte ^= (dd & 7) << 4;
        *(u16*)((char*)lVt + byte) = pv[j];
      }
    }
    __syncthreads();
    // S = K Q^T  (wave w owns t rows w*16..w*16+15, all 64 s cols)
    bf16x8 af[2];
    {
      int row = w * 16 + (lane & 15);
#pragma unroll
      for (int kk = 0; kk < 2; ++kk) {
        int cu = kk * 4 + (lane >> 4);
        af[kk] = *(const bf16x8*)((const char*)lK + row * 128 + ((cu ^ (row & 7)) << 4));
      }
    }
    f32x4 sacc[4] = {};
#pragma unroll
    for (int ni = 0; ni < 4; ++ni) {
      int row = ni * 16 + (lane & 15);
#pragma unroll
      for (int kk = 0; kk < 2; ++kk) {
        int cu = kk * 4 + (lane >> 4);
        bf16x8 bq = *(const bf16x8*)((const char*)lQ + row * 128 + ((cu ^ (row & 7)) << 4));
        sacc[ni] = __builtin_amdgcn_mfma_f32_16x16x32_bf16(af[kk], bq, sacc[ni], 0, 0, 0);
      }
    }
    // mask + online softmax (rows live on 16-lane groups)
    const int tg0 = t0 + w * 16 + ((lane >> 4) << 2);
    float pm[4][4];
    float rmax[4] = {-1e30f, -1e30f, -1e30f, -1e30f};
#pragma unroll
    for (int ni = 0; ni < 4; ++ni) {
      int sg = s0 + ni * 16 + (lane & 15);
#pragma unroll
      for (int r = 0; r < 4; ++r) {
        float vv = sacc[ni][r] * SCALE;
        if (sg > tg0 + r) vv = -1e30f;
        pm[ni][r] = vv;
        rmax[r] = fmaxf(rmax[r], vv);
      }
    }
#pragma unroll
    for (int r = 0; r < 4; ++r) {
#pragma unroll
      for (int off = 1; off < 16; off <<= 1)
        rmax[r] = fmaxf(rmax[r], __shfl_xor(rmax[r], off));
    }
    float alpha[4], rsum[4];
#pragma unroll
    for (int r = 0; r < 4; ++r) {
      float mnew = fmaxf(mrow[r], rmax[r]);
      alpha[r] = __expf(mrow[r] - mnew);
      mrow[r] = mnew;
      rsum[r] = 0.f;
    }
#pragma unroll
    for (int ni = 0; ni < 4; ++ni)
#pragma unroll
      for (int r = 0; r < 4; ++r) {
        float p = __expf(pm[ni][r] - mrow[r]);
        pm[ni][r] = p;
        rsum[r] += p;
      }
#pragma unroll
    for (int r = 0; r < 4; ++r) {
#pragma unroll
      for (int off = 1; off < 16; off <<= 1)
        rsum[r] += __shfl_xor(rsum[r], off);
      lrow[r] = lrow[r] * alpha[r] + rsum[r];
    }
#pragma unroll
    for (int nd = 0; nd < 4; ++nd)
#pragma unroll
      for (int r = 0; r < 4; ++r) oacc[nd][r] *= alpha[r];
    // P -> per-wave LDS (bf16, swizzled); same-wave write->read, no barrier needed
    u16* lPw = lP + w * 1024;
#pragma unroll
    for (int ni = 0; ni < 4; ++ni) {
      int scol = ni * 16 + (lane & 15);
#pragma unroll
      for (int r = 0; r < 4; ++r) {
        int trow = ((lane >> 4) << 2) + r;
        int byte = trow * 128 + scol * 2;
        byte ^= (trow & 7) << 4;
        *(u16*)((char*)lPw + byte) = f2bf(pm[ni][r]);
      }
    }
    // O += P @ V
    bf16x8 pa[2];
    {
      int trow = lane & 15;
#pragma unroll
      for (int kk = 0; kk < 2; ++kk) {
        int cu = kk * 4 + (lane >> 4);
        pa[kk] = *(const bf16x8*)((const char*)lPw + trow * 128 + ((cu ^ (trow & 7)) << 4));
      }
    }
#pragma unroll
    for (int nd = 0; nd < 4; ++nd) {
      int drow = nd * 16 + (lane & 15);
#pragma unroll
      for (int kk = 0; kk < 2; ++kk) {
        int cu = kk * 4 + (lane >> 4);
        bf16x8 vb = *(const bf16x8*)((const char*)lVt + drow * 128 + ((cu ^ (drow & 7)) << 4));
        oacc[nd] = __builtin_amdgcn_mfma_f32_16x16x32_bf16(pa[kk], vb, oacc[nd], 0, 0, 0);
      }
    }
  }
  // epilogue: attn [b][t][h*64+d] bf16
  const int b = bh / NHEAD, h = bh - (bh / NHEAD) * NHEAD;
#pragma unroll
  for (int r = 0; r < 4; ++r) {
    int t = t0 + w * 16 + ((lane >> 4) << 2) + r;
    float inv = 1.0f / lrow[r];
#pragma unroll
    for (int nd = 0; nd < 4; ++nd) {
      int col = h * 64 + nd * 16 + (lane & 15);
      attnb[((size_t)(b * T_SZ + t)) * C_EMB + col] = f2bf(oacc[nd][r] * inv);
    }
  }
}

// ---------------- out projection: [65536,384] x [384,384] + bias -> fp32 ----
__global__ __launch_bounds__(256) void out_gemm(const u16* __restrict__ a,
                                                const u16* __restrict__ wt,
                                                const float* __restrict__ bias,
                                                float* __restrict__ out) {
  __shared__ __align__(16) u16 lA[128 * 64];
  __shared__ __align__(16) u16 lB[128 * 64];
  const int tid = threadIdx.x;
  const int lane = tid & 63, w = tid >> 6;
  // T1: 1536 wgs = 8 x 192; nt-fastest
  int bid = blockIdx.x;
  int nb = (bid & 7) * 192 + (bid >> 3);
  int mt = nb / 3, nt = nb - mt * 3;
  const int n0 = nt * 128, m0 = mt * 128;
  const int wr = w >> 1, wc = w & 1;
  f32x4 acc[4][4] = {};
  for (int kt = 0; kt < 6; ++kt) {
    const int k0 = kt * 64;
    __syncthreads();
#pragma unroll
    for (int it = 0; it < 4; ++it) {
      int ub = it * 256 + w * 64;
      int u = ub + lane;
      int row = u >> 3, cu = u & 7;
      int koff = k0 + ((cu ^ (row & 7)) << 3);
      gload_lds16(a + (size_t)(m0 + row) * C_EMB + koff, lA + ub * 8);
      gload_lds16(wt + (size_t)(n0 + row) * C_EMB + koff, lB + ub * 8);
    }
    __syncthreads();
    bf16x8 af[4][2], bfr[4][2];
#pragma unroll
    for (int mi = 0; mi < 4; ++mi) {
      int row = wr * 64 + mi * 16 + (lane & 15);
#pragma unroll
      for (int kk = 0; kk < 2; ++kk) {
        int cu = kk * 4 + (lane >> 4);
        af[mi][kk] = *(const bf16x8*)((const char*)lA + row * 128 + ((cu ^ (row & 7)) << 4));
      }
    }
#pragma unroll
    for (int ni = 0; ni < 4; ++ni) {
      int row = wc * 64 + ni * 16 + (lane & 15);
#pragma unroll
      for (int kk = 0; kk < 2; ++kk) {
        int cu = kk * 4 + (lane >> 4);
        bfr[ni][kk] = *(const bf16x8*)((const char*)lB + row * 128 + ((cu ^ (row & 7)) << 4));
      }
    }
#pragma unroll
    for (int kk = 0; kk < 2; ++kk)
#pragma unroll
      for (int mi = 0; mi < 4; ++mi)
#pragma unroll
        for (int ni = 0; ni < 4; ++ni)
          acc[mi][ni] = __builtin_amdgcn_mfma_f32_16x16x32_bf16(
              af[mi][kk], bfr[ni][kk], acc[mi][ni], 0, 0, 0);
  }
#pragma unroll
  for (int ni = 0; ni < 4; ++ni) {
    int gn = n0 + wc * 64 + ni * 16 + (lane & 15);
    float bv = bias[gn];
#pragma unroll
    for (int mi = 0; mi < 4; ++mi) {
      int gm0 = m0 + wr * 64 + mi * 16 + ((lane >> 4) << 2);
#pragma unroll
      for (int r = 0; r < 4; ++r)
        out[(size_t)(gm0 + r) * C_EMB + gn] = acc[mi][ni][r] + bv;
    }
  }
}

extern "C" void kernel_launch(void* const* d_in, const int* in_sizes, int n_in,
                              void* d_out, int out_size, void* d_ws, size_t ws_size,
                              hipStream_t stream) {
  const float* x = (const float*)d_in[0];
  const float* wk = (const float*)d_in[1];
  const float* wq = (const float*)d_in[2];
  const float* wv = (const float*)d_in[3];
  const float* wproj = (const float*)d_in[4];
  const float* bproj = (const float*)d_in[5];
  float* out = (float*)d_out;
  u16* ws = (u16*)d_ws;
  u16* kqv = ws;                               // 3 * BHTD bf16
  u16* attnb = ws + 3 * (size_t)BHTD;          // BHTD bf16 (attn out)
  u16* xb = attnb;                             // aliases attnb: xb dead before attn writes
  u16* wqkvt = attnb + (size_t)BHTD;           // 1152*384
  u16* wprojt = wqkvt + (size_t)N3 * C_EMB;    // 384*384
  prep_weights<<<2304, 256, 0, stream>>>(wk, wq, wv, wproj, wqkvt, wprojt);
  prep_x<<<12288, 256, 0, stream>>>(x, xb);
  qkv_gemm<<<4608, 256, 0, stream>>>(xb, wqkvt, kqv);
  attn_kernel<<<dim3(4, 1536), 256, 0, stream>>>(kqv, attnb);
  out_gemm<<<1536, 256, 0, stream>>>(attnb, wprojt, bproj, out);
}

// Round 3
// 214.831 us; speedup vs baseline: 1.5959x; 1.2120x over previous
//
#include <hip/hip_runtime.h>

typedef unsigned short u16;
typedef __bf16 bf16x8 __attribute__((ext_vector_type(8)));
typedef float f32x4 __attribute__((ext_vector_type(4)));

#define B_SZ 256
#define T_SZ 256
#define C_EMB 384
#define NHEAD 6
#define DHEAD 64
#define N3 1152
#define BHTD 25165824   // B*H*T*D elements per tensor
#define SCALE 0.05103103630798287f  // 384^-0.5

__device__ __forceinline__ u16 f2bf(float f) {
  unsigned u = __float_as_uint(f);
  u += 0x7FFFu + ((u >> 16) & 1u);   // RNE
  return (u16)(u >> 16);
}

__device__ __forceinline__ void gload_lds16(const void* g, void* l) {
  __builtin_amdgcn_global_load_lds((const __attribute__((address_space(1))) void*)g,
                                   (__attribute__((address_space(3))) void*)l, 16, 0, 0);
}

// ---------------- weight prep: bf16 + transpose to [n][k]; K rows pre-scaled
__global__ __launch_bounds__(256) void prep_weights(
    const float* __restrict__ wk, const float* __restrict__ wq,
    const float* __restrict__ wv, const float* __restrict__ wproj,
    u16* __restrict__ wqkvt, u16* __restrict__ wprojt) {
  int i = blockIdx.x * 256 + threadIdx.x;
  if (i < N3 * C_EMB) {
    int n = i / C_EMB, c = i - n * C_EMB;
    int tensor = n >= 768 ? 2 : (n >= 384 ? 1 : 0);
    int r = n - tensor * 384;
    int h = r >> 6, d = r & 63;
    const float* w = tensor == 0 ? wk : (tensor == 1 ? wq : wv);
    float val = w[(h * C_EMB + c) * DHEAD + d];
    if (tensor == 0) val *= SCALE;   // fold 1/sqrt(C) into K
    wqkvt[i] = f2bf(val);
  } else {
    int ii = i - N3 * C_EMB;
    if (ii < C_EMB * C_EMB) {
      int n = ii / C_EMB, c = ii - n * C_EMB;
      wprojt[ii] = f2bf(wproj[c * C_EMB + n]);  // transpose
    }
  }
}

// ---------------- x -> bf16 ----------
__global__ __launch_bounds__(256) void prep_x(const float* __restrict__ x,
                                              u16* __restrict__ xb) {
  int i = blockIdx.x * 256 + threadIdx.x;   // unit of 8 floats
  float4 f0 = ((const float4*)x)[i * 2];
  float4 f1 = ((const float4*)x)[i * 2 + 1];
  uint4 p;
  p.x = (unsigned)f2bf(f0.x) | ((unsigned)f2bf(f0.y) << 16);
  p.y = (unsigned)f2bf(f0.z) | ((unsigned)f2bf(f0.w) << 16);
  p.z = (unsigned)f2bf(f1.x) | ((unsigned)f2bf(f1.y) << 16);
  p.w = (unsigned)f2bf(f1.z) | ((unsigned)f2bf(f1.w) << 16);
  ((uint4*)xb)[i] = p;
}

// ---------------- QKV GEMM -> K,Q as [b][h][t][d]; V as [b][h][d][t] (transposed)
__global__ __launch_bounds__(256) void qkv_gemm(const u16* __restrict__ xb,
                                                const u16* __restrict__ wt,
                                                u16* __restrict__ kqv) {
  __shared__ __align__(16) u16 lA[2][128 * 64];
  __shared__ __align__(16) u16 lB[2][128 * 64];
  const int tid = threadIdx.x;
  const int lane = tid & 63, w = tid >> 6;
  int bid = blockIdx.x;
  int nb = (bid & 7) * 576 + (bid >> 3);
  int mt = nb / 9, nt = nb - mt * 9;
  const int n0 = nt * 128, m0 = mt * 128;
  const int wr = w >> 1, wc = w & 1;
  f32x4 acc[4][4] = {};

#define QSTAGE(buf, kt_) { \
    int k0_ = (kt_) * 64; \
    _Pragma("unroll") for (int it = 0; it < 4; ++it) { \
      int ub = it * 256 + w * 64; int u = ub + lane; \
      int row = u >> 3, cu = u & 7; \
      int koff = k0_ + ((cu ^ (row & 7)) << 3); \
      gload_lds16(xb + (size_t)(m0 + row) * C_EMB + koff, lA[buf] + ub * 8); \
      gload_lds16(wt + (size_t)(n0 + row) * C_EMB + koff, lB[buf] + ub * 8); \
    } }

  QSTAGE(0, 0);
  asm volatile("s_waitcnt vmcnt(0)" ::: "memory");
  asm volatile("s_barrier" ::: "memory");
  int cur = 0;
  for (int kt = 0; kt < 6; ++kt) {
    if (kt < 5) { QSTAGE(cur ^ 1, kt + 1); }
    bf16x8 af[4][2], bfr[4][2];
#pragma unroll
    for (int mi = 0; mi < 4; ++mi) {
      int row = wr * 64 + mi * 16 + (lane & 15);
#pragma unroll
      for (int kk = 0; kk < 2; ++kk) {
        int cu = kk * 4 + (lane >> 4);
        af[mi][kk] = *(const bf16x8*)((const char*)lA[cur] + row * 128 + ((cu ^ (row & 7)) << 4));
      }
    }
#pragma unroll
    for (int ni = 0; ni < 4; ++ni) {
      int row = wc * 64 + ni * 16 + (lane & 15);
#pragma unroll
      for (int kk = 0; kk < 2; ++kk) {
        int cu = kk * 4 + (lane >> 4);
        bfr[ni][kk] = *(const bf16x8*)((const char*)lB[cur] + row * 128 + ((cu ^ (row & 7)) << 4));
      }
    }
#pragma unroll
    for (int kk = 0; kk < 2; ++kk)
#pragma unroll
      for (int mi = 0; mi < 4; ++mi)
#pragma unroll
        for (int ni = 0; ni < 4; ++ni)
          acc[mi][ni] = __builtin_amdgcn_mfma_f32_16x16x32_bf16(
              af[mi][kk], bfr[ni][kk], acc[mi][ni], 0, 0, 0);
    asm volatile("s_waitcnt vmcnt(0)" ::: "memory");
    asm volatile("s_barrier" ::: "memory");
    cur ^= 1;
  }
#undef QSTAGE

  const int tensor = nt / 3;  // tiles are tensor-aligned (384 = 3*128)
  if (tensor == 2) {
    // V^T store: vt[((b*6+h)*64 + d)*256 + t], 4 t-contiguous values packed
    u16* vt = kqv + 2 * (size_t)BHTD;
#pragma unroll
    for (int ni = 0; ni < 4; ++ni) {
      int r2 = n0 + wc * 64 + ni * 16 + (lane & 15) - 768;
      int h = r2 >> 6, d = r2 & 63;
#pragma unroll
      for (int mi = 0; mi < 4; ++mi) {
        int gm0 = m0 + wr * 64 + mi * 16 + ((lane >> 4) << 2);
        int b = gm0 >> 8, tt = gm0 & 255;
        ushort4 pk;
        pk.x = f2bf(acc[mi][ni][0]);
        pk.y = f2bf(acc[mi][ni][1]);
        pk.z = f2bf(acc[mi][ni][2]);
        pk.w = f2bf(acc[mi][ni][3]);
        *(ushort4*)(vt + ((size_t)(b * NHEAD + h) * 64 + d) * 256 + tt) = pk;
      }
    }
  } else {
#pragma unroll
    for (int ni = 0; ni < 4; ++ni) {
      int gn = n0 + wc * 64 + ni * 16 + (lane & 15);
      int r2 = gn - tensor * 384;
      int h = r2 >> 6, d = r2 & 63;
#pragma unroll
      for (int mi = 0; mi < 4; ++mi) {
        int gm0 = m0 + wr * 64 + mi * 16 + ((lane >> 4) << 2);
#pragma unroll
        for (int r = 0; r < 4; ++r) {
          int m = gm0 + r;
          int b = m >> 8, t = m & 255;
          kqv[(size_t)tensor * BHTD + ((((b * NHEAD + h) << 8) + t) << 6) + d] =
              f2bf(acc[mi][ni][r]);
        }
      }
    }
  }
}

// ---------------- causal flash attention, S[t,s] = Ksc[t]·Q[s] ----
// 128 t-rows per block, 8 waves x 16 rows, KV double-buffered, V pre-transposed.
__global__ __launch_bounds__(512, 4) void attn_kernel(const u16* __restrict__ kqv,
                                                      u16* __restrict__ attnb) {
  __shared__ __align__(16) u16 lK[128 * 64];
  __shared__ __align__(16) u16 lQ[2][64 * 64];
  __shared__ __align__(16) u16 lVt[2][64 * 64];
  __shared__ __align__(16) char lP[8 * 16 * 144];
  const int tid = threadIdx.x;
  const int lane = tid & 63, w = tid >> 6;
  int bid = blockIdx.x;                       // 3072 = 8 * 384
  int id = (bid & 7) * 384 + (bid >> 3);
  const int bh = id >> 1, tt = id & 1;
  const int t0 = tt * 128;
  const u16* Kb = kqv + (size_t)bh * (T_SZ * DHEAD);
  const u16* Qb = kqv + (size_t)BHTD + (size_t)bh * (T_SZ * DHEAD);
  const u16* Vb = kqv + 2 * (size_t)BHTD + (size_t)bh * (DHEAD * T_SZ);  // [d][t]

#define STAGE_Q(buf, ss) { int ub = w * 64; int u = ub + lane; \
    int row = u >> 3, cu = u & 7; \
    gload_lds16(Qb + (size_t)((ss) + row) * DHEAD + ((cu ^ (row & 7)) << 3), lQ[buf] + ub * 8); }
#define STAGE_V(buf, ss) { int ub = w * 64; int u = ub + lane; \
    int row = u >> 3, cu = u & 7; \
    gload_lds16(Vb + (size_t)row * T_SZ + (ss) + ((cu ^ (row & 7)) << 3), lVt[buf] + ub * 8); }

  // prologue: K tile (128 rows) + Q0/V0
#pragma unroll
  for (int it = 0; it < 2; ++it) {
    int ub = it * 512 + w * 64;
    int u = ub + lane;
    int row = u >> 3, cu = u & 7;
    gload_lds16(Kb + (size_t)(t0 + row) * DHEAD + ((cu ^ (row & 7)) << 3), lK + ub * 8);
  }
  STAGE_Q(0, 0);
  STAGE_V(0, 0);
  asm volatile("s_waitcnt vmcnt(0)" ::: "memory");
  asm volatile("s_barrier" ::: "memory");

  const int t0w = t0 + w * 16;                // wave's min t-row
  const int tg0 = t0w + ((lane >> 4) << 2);   // lane's first t-row
  bf16x8 af[2];
  {
    int arow = w * 16 + (lane & 15);
#pragma unroll
    for (int kk = 0; kk < 2; ++kk) {
      int cu = kk * 4 + (lane >> 4);
      af[kk] = *(const bf16x8*)((const char*)lK + arow * 128 + ((cu ^ (arow & 7)) << 4));
    }
  }
  char* lPw = lP + w * (16 * 144);
  f32x4 oacc[4] = {};
  float mrow[4] = {-1e30f, -1e30f, -1e30f, -1e30f};
  float lrowp[4] = {0.f, 0.f, 0.f, 0.f};
  const int nst = 2 * tt + 2;
  int cur = 0;
  for (int si = 0; si < nst; ++si) {
    const int s0 = si << 6;
    if (si + 1 < nst) { STAGE_Q(cur ^ 1, s0 + 64); STAGE_V(cur ^ 1, s0 + 64); }
    if (s0 <= t0w + 15) {                     // wave has unmasked rows in this tile
      f32x4 sacc[4] = {};
#pragma unroll
      for (int ni = 0; ni < 4; ++ni) {
        int row = ni * 16 + (lane & 15);
#pragma unroll
        for (int kk = 0; kk < 2; ++kk) {
          int cu = kk * 4 + (lane >> 4);
          bf16x8 bq = *(const bf16x8*)((const char*)lQ[cur] + row * 128 + ((cu ^ (row & 7)) << 4));
          sacc[ni] = __builtin_amdgcn_mfma_f32_16x16x32_bf16(af[kk], bq, sacc[ni], 0, 0, 0);
        }
      }
      float pm[4][4];
      float rmax[4] = {-1e30f, -1e30f, -1e30f, -1e30f};
      if (s0 + 63 > t0w) {                    // diagonal tile: apply causal mask
#pragma unroll
        for (int ni = 0; ni < 4; ++ni) {
          int sg = s0 + ni * 16 + (lane & 15);
#pragma unroll
          for (int r = 0; r < 4; ++r) {
            float vv = sacc[ni][r];
            if (sg > tg0 + r) vv = -1e30f;
            pm[ni][r] = vv;
            rmax[r] = fmaxf(rmax[r], vv);
          }
        }
      } else {
#pragma unroll
        for (int ni = 0; ni < 4; ++ni)
#pragma unroll
          for (int r = 0; r < 4; ++r) {
            float vv = sacc[ni][r];
            pm[ni][r] = vv;
            rmax[r] = fmaxf(rmax[r], vv);
          }
      }
#pragma unroll
      for (int r = 0; r < 4; ++r) {
#pragma unroll
        for (int off = 1; off < 16; off <<= 1)
          rmax[r] = fmaxf(rmax[r], __shfl_xor(rmax[r], off));
      }
      // defer-max (T13): skip rescale when max growth <= 8
      bool small = (rmax[0] - mrow[0] <= 8.f) && (rmax[1] - mrow[1] <= 8.f) &&
                   (rmax[2] - mrow[2] <= 8.f) && (rmax[3] - mrow[3] <= 8.f);
      if (!__all(small)) {
#pragma unroll
        for (int r = 0; r < 4; ++r) {
          float mnew = fmaxf(mrow[r], rmax[r]);
          float alpha = __expf(mrow[r] - mnew);
          mrow[r] = mnew;
          lrowp[r] *= alpha;
#pragma unroll
          for (int nd = 0; nd < 4; ++nd) oacc[nd][r] *= alpha;
        }
      }
#pragma unroll
      for (int ni = 0; ni < 4; ++ni)
#pragma unroll
        for (int r = 0; r < 4; ++r) {
          float p = __expf(pm[ni][r] - mrow[r]);
          pm[ni][r] = p;
          lrowp[r] += p;                       // per-lane partial row-sum
        }
      // P -> per-wave LDS (stride 144: aligned 16B reads, bank-spread)
#pragma unroll
      for (int ni = 0; ni < 4; ++ni) {
        int scol = ni * 16 + (lane & 15);
#pragma unroll
        for (int r = 0; r < 4; ++r) {
          int trow = ((lane >> 4) << 2) + r;
          *(u16*)(lPw + trow * 144 + scol * 2) = f2bf(pm[ni][r]);
        }
      }
      bf16x8 pa[2];
      {
        int trow = lane & 15;
#pragma unroll
        for (int kk = 0; kk < 2; ++kk) {
          int cu = kk * 4 + (lane >> 4);
          pa[kk] = *(const bf16x8*)(lPw + trow * 144 + cu * 16);
        }
      }
#pragma unroll
      for (int nd = 0; nd < 4; ++nd) {
        int drow = nd * 16 + (lane & 15);
#pragma unroll
        for (int kk = 0; kk < 2; ++kk) {
          int cu = kk * 4 + (lane >> 4);
          bf16x8 vb = *(const bf16x8*)((const char*)lVt[cur] + drow * 128 + ((cu ^ (drow & 7)) << 4));
          oacc[nd] = __builtin_amdgcn_mfma_f32_16x16x32_bf16(pa[kk], vb, oacc[nd], 0, 0, 0);
        }
      }
    }
    asm volatile("s_waitcnt vmcnt(0)" ::: "memory");
    asm volatile("s_barrier" ::: "memory");
    cur ^= 1;
  }
#undef STAGE_Q
#undef STAGE_V
  // final cross-lane row-sum reduce (once, not per tile)
#pragma unroll
  for (int r = 0; r < 4; ++r) {
#pragma unroll
    for (int off = 1; off < 16; off <<= 1)
      lrowp[r] += __shfl_xor(lrowp[r], off);
  }
  const int b = bh / NHEAD, h = bh - (bh / NHEAD) * NHEAD;
#pragma unroll
  for (int r = 0; r < 4; ++r) {
    int t = tg0 + r;
    float inv = 1.0f / lrowp[r];
#pragma unroll
    for (int nd = 0; nd < 4; ++nd) {
      int col = h * 64 + nd * 16 + (lane & 15);
      attnb[((size_t)(b * T_SZ + t)) * C_EMB + col] = f2bf(oacc[nd][r] * inv);
    }
  }
}

// ---------------- out projection: [65536,384] x [384,384] + bias -> fp32 ----
__global__ __launch_bounds__(256) void out_gemm(const u16* __restrict__ a,
                                                const u16* __restrict__ wt,
                                                const float* __restrict__ bias,
                                                float* __restrict__ out) {
  __shared__ __align__(16) u16 lA[2][128 * 64];
  __shared__ __align__(16) u16 lB[2][128 * 64];
  const int tid = threadIdx.x;
  const int lane = tid & 63, w = tid >> 6;
  int bid = blockIdx.x;
  int nb = (bid & 7) * 192 + (bid >> 3);
  int mt = nb / 3, nt = nb - mt * 3;
  const int n0 = nt * 128, m0 = mt * 128;
  const int wr = w >> 1, wc = w & 1;
  f32x4 acc[4][4] = {};

#define OSTAGE(buf, kt_) { \
    int k0_ = (kt_) * 64; \
    _Pragma("unroll") for (int it = 0; it < 4; ++it) { \
      int ub = it * 256 + w * 64; int u = ub + lane; \
      int row = u >> 3, cu = u & 7; \
      int koff = k0_ + ((cu ^ (row & 7)) << 3); \
      gload_lds16(a + (size_t)(m0 + row) * C_EMB + koff, lA[buf] + ub * 8); \
      gload_lds16(wt + (size_t)(n0 + row) * C_EMB + koff, lB[buf] + ub * 8); \
    } }

  OSTAGE(0, 0);
  asm volatile("s_waitcnt vmcnt(0)" ::: "memory");
  asm volatile("s_barrier" ::: "memory");
  int cur = 0;
  for (int kt = 0; kt < 6; ++kt) {
    if (kt < 5) { OSTAGE(cur ^ 1, kt + 1); }
    bf16x8 af[4][2], bfr[4][2];
#pragma unroll
    for (int mi = 0; mi < 4; ++mi) {
      int row = wr * 64 + mi * 16 + (lane & 15);
#pragma unroll
      for (int kk = 0; kk < 2; ++kk) {
        int cu = kk * 4 + (lane >> 4);
        af[mi][kk] = *(const bf16x8*)((const char*)lA[cur] + row * 128 + ((cu ^ (row & 7)) << 4));
      }
    }
#pragma unroll
    for (int ni = 0; ni < 4; ++ni) {
      int row = wc * 64 + ni * 16 + (lane & 15);
#pragma unroll
      for (int kk = 0; kk < 2; ++kk) {
        int cu = kk * 4 + (lane >> 4);
        bfr[ni][kk] = *(const bf16x8*)((const char*)lB[cur] + row * 128 + ((cu ^ (row & 7)) << 4));
      }
    }
#pragma unroll
    for (int kk = 0; kk < 2; ++kk)
#pragma unroll
      for (int mi = 0; mi < 4; ++mi)
#pragma unroll
        for (int ni = 0; ni < 4; ++ni)
          acc[mi][ni] = __builtin_amdgcn_mfma_f32_16x16x32_bf16(
              af[mi][kk], bfr[ni][kk], acc[mi][ni], 0, 0, 0);
    asm volatile("s_waitcnt vmcnt(0)" ::: "memory");
    asm volatile("s_barrier" ::: "memory");
    cur ^= 1;
  }
#undef OSTAGE
#pragma unroll
  for (int ni = 0; ni < 4; ++ni) {
    int gn = n0 + wc * 64 + ni * 16 + (lane & 15);
    float bv = bias[gn];
#pragma unroll
    for (int mi = 0; mi < 4; ++mi) {
      int gm0 = m0 + wr * 64 + mi * 16 + ((lane >> 4) << 2);
#pragma unroll
      for (int r = 0; r < 4; ++r)
        out[(size_t)(gm0 + r) * C_EMB + gn] = acc[mi][ni][r] + bv;
    }
  }
}

extern "C" void kernel_launch(void* const* d_in, const int* in_sizes, int n_in,
                              void* d_out, int out_size, void* d_ws, size_t ws_size,
                              hipStream_t stream) {
  const float* x = (const float*)d_in[0];
  const float* wk = (const float*)d_in[1];
  const float* wq = (const float*)d_in[2];
  const float* wv = (const float*)d_in[3];
  const float* wproj = (const float*)d_in[4];
  const float* bproj = (const float*)d_in[5];
  float* out = (float*)d_out;
  u16* ws = (u16*)d_ws;
  u16* kqv = ws;                               // 3 * BHTD bf16 (K,Q [bhtd]; V [bhdt])
  u16* attnb = ws + 3 * (size_t)BHTD;          // BHTD bf16 (attn out)
  u16* xb = attnb;                             // aliases attnb: xb dead before attn writes
  u16* wqkvt = attnb + (size_t)BHTD;           // 1152*384
  u16* wprojt = wqkvt + (size_t)N3 * C_EMB;    // 384*384
  prep_weights<<<2304, 256, 0, stream>>>(wk, wq, wv, wproj, wqkvt, wprojt);
  prep_x<<<12288, 256, 0, stream>>>(x, xb);
  qkv_gemm<<<4608, 256, 0, stream>>>(xb, wqkvt, kqv);
  attn_kernel<<<3072, 512, 0, stream>>>(kqv, attnb);
  out_gemm<<<1536, 256, 0, stream>>>(attnb, wprojt, bproj, out);
}

// Round 4
// 206.764 us; speedup vs baseline: 1.6582x; 1.0390x over previous
//
#include <hip/hip_runtime.h>

typedef unsigned short u16;
typedef __bf16 bf16x8 __attribute__((ext_vector_type(8)));
typedef float f32x4 __attribute__((ext_vector_type(4)));

#define B_SZ 256
#define T_SZ 256
#define C_EMB 384
#define NHEAD 6
#define DHEAD 64
#define N3 1152
#define BHTD 25165824   // B*H*T*D elements per tensor
#define SCALE 0.05103103630798287f  // 384^-0.5

__device__ __forceinline__ u16 f2bf(float f) {
  unsigned u = __float_as_uint(f);
  u += 0x7FFFu + ((u >> 16) & 1u);   // RNE
  return (u16)(u >> 16);
}

__device__ __forceinline__ void gload_lds16(const void* g, void* l) {
  __builtin_amdgcn_global_load_lds((const __attribute__((address_space(1))) void*)g,
                                   (__attribute__((address_space(3))) void*)l, 16, 0, 0);
}

// ---------------- weight prep: bf16 + transpose to [n][k]; K rows pre-scaled
__global__ __launch_bounds__(256) void prep_weights(
    const float* __restrict__ wk, const float* __restrict__ wq,
    const float* __restrict__ wv, const float* __restrict__ wproj,
    u16* __restrict__ wqkvt, u16* __restrict__ wprojt) {
  int i = blockIdx.x * 256 + threadIdx.x;
  if (i < N3 * C_EMB) {
    int n = i / C_EMB, c = i - n * C_EMB;
    int tensor = n >= 768 ? 2 : (n >= 384 ? 1 : 0);
    int r = n - tensor * 384;
    int h = r >> 6, d = r & 63;
    const float* w = tensor == 0 ? wk : (tensor == 1 ? wq : wv);
    float val = w[(h * C_EMB + c) * DHEAD + d];
    if (tensor == 0) val *= SCALE;   // fold 1/sqrt(C) into K
    wqkvt[i] = f2bf(val);
  } else {
    int ii = i - N3 * C_EMB;
    if (ii < C_EMB * C_EMB) {
      int n = ii / C_EMB, c = ii - n * C_EMB;
      wprojt[ii] = f2bf(wproj[c * C_EMB + n]);  // transpose
    }
  }
}

// ---------------- x -> bf16 ----------
__global__ __launch_bounds__(256) void prep_x(const float* __restrict__ x,
                                              u16* __restrict__ xb) {
  int i = blockIdx.x * 256 + threadIdx.x;   // unit of 8 floats
  float4 f0 = ((const float4*)x)[i * 2];
  float4 f1 = ((const float4*)x)[i * 2 + 1];
  uint4 p;
  p.x = (unsigned)f2bf(f0.x) | ((unsigned)f2bf(f0.y) << 16);
  p.y = (unsigned)f2bf(f0.z) | ((unsigned)f2bf(f0.w) << 16);
  p.z = (unsigned)f2bf(f1.x) | ((unsigned)f2bf(f1.y) << 16);
  p.w = (unsigned)f2bf(f1.z) | ((unsigned)f2bf(f1.w) << 16);
  ((uint4*)xb)[i] = p;
}

// ---------------- QKV GEMM -> K,Q as [b][h][t][d]; V as [b][h][d][t] (transposed)
// Counted-vmcnt double-barrier K-loop (T4): next tile's loads stay in flight
// across both barriers; each wave retires ITS prior loads before barrier 1.
__global__ __launch_bounds__(256) void qkv_gemm(const u16* __restrict__ xb,
                                                const u16* __restrict__ wt,
                                                u16* __restrict__ kqv) {
  __shared__ __align__(16) u16 lA[2][128 * 64];
  __shared__ __align__(16) u16 lB[2][128 * 64];
  const int tid = threadIdx.x;
  const int lane = tid & 63, w = tid >> 6;
  int bid = blockIdx.x;
  int nb = (bid & 7) * 576 + (bid >> 3);
  int mt = nb / 9, nt = nb - mt * 9;
  const int n0 = nt * 128, m0 = mt * 128;
  const int wr = w >> 1, wc = w & 1;
  f32x4 acc[4][4] = {};

#define QSTAGE(buf, kt_) { \
    int k0_ = (kt_) * 64; \
    _Pragma("unroll") for (int it = 0; it < 4; ++it) { \
      int ub = it * 256 + w * 64; int u = ub + lane; \
      int row = u >> 3, cu = u & 7; \
      int koff = k0_ + ((cu ^ (row & 7)) << 3); \
      gload_lds16(xb + (size_t)(m0 + row) * C_EMB + koff, lA[buf] + ub * 8); \
      gload_lds16(wt + (size_t)(n0 + row) * C_EMB + koff, lB[buf] + ub * 8); \
    } }

  QSTAGE(0, 0);                                // 8 loads in flight
  int cur = 0;
  for (int kt = 0; kt < 6; ++kt) {
    if (kt < 5) {
      QSTAGE(cur ^ 1, kt + 1);                 // 16 in flight
      asm volatile("s_waitcnt vmcnt(8)" ::: "memory");   // cur's 8 landed
    } else {
      asm volatile("s_waitcnt vmcnt(0)" ::: "memory");
    }
    asm volatile("s_barrier" ::: "memory");    // all waves' cur loads visible
    bf16x8 af[4][2], bfr[4][2];
#pragma unroll
    for (int mi = 0; mi < 4; ++mi) {
      int row = wr * 64 + mi * 16 + (lane & 15);
#pragma unroll
      for (int kk = 0; kk < 2; ++kk) {
        int cu = kk * 4 + (lane >> 4);
        af[mi][kk] = *(const bf16x8*)((const char*)lA[cur] + row * 128 + ((cu ^ (row & 7)) << 4));
      }
    }
#pragma unroll
    for (int ni = 0; ni < 4; ++ni) {
      int row = wc * 64 + ni * 16 + (lane & 15);
#pragma unroll
      for (int kk = 0; kk < 2; ++kk) {
        int cu = kk * 4 + (lane >> 4);
        bfr[ni][kk] = *(const bf16x8*)((const char*)lB[cur] + row * 128 + ((cu ^ (row & 7)) << 4));
      }
    }
#pragma unroll
    for (int kk = 0; kk < 2; ++kk)
#pragma unroll
      for (int mi = 0; mi < 4; ++mi)
#pragma unroll
        for (int ni = 0; ni < 4; ++ni)
          acc[mi][ni] = __builtin_amdgcn_mfma_f32_16x16x32_bf16(
              af[mi][kk], bfr[ni][kk], acc[mi][ni], 0, 0, 0);
    asm volatile("s_barrier" ::: "memory");    // buf[cur] safe to overwrite
    cur ^= 1;
  }
#undef QSTAGE

  const int tensor = nt / 3;  // tiles are tensor-aligned (384 = 3*128)
  if (tensor == 2) {
    // V^T store: vt[((b*6+h)*64 + d)*256 + t], 4 t-contiguous values packed
    u16* vt = kqv + 2 * (size_t)BHTD;
#pragma unroll
    for (int ni = 0; ni < 4; ++ni) {
      int r2 = n0 + wc * 64 + ni * 16 + (lane & 15) - 768;
      int h = r2 >> 6, d = r2 & 63;
#pragma unroll
      for (int mi = 0; mi < 4; ++mi) {
        int gm0 = m0 + wr * 64 + mi * 16 + ((lane >> 4) << 2);
        int b = gm0 >> 8, tt = gm0 & 255;
        ushort4 pk;
        pk.x = f2bf(acc[mi][ni][0]);
        pk.y = f2bf(acc[mi][ni][1]);
        pk.z = f2bf(acc[mi][ni][2]);
        pk.w = f2bf(acc[mi][ni][3]);
        *(ushort4*)(vt + ((size_t)(b * NHEAD + h) * 64 + d) * 256 + tt) = pk;
      }
    }
  } else {
#pragma unroll
    for (int ni = 0; ni < 4; ++ni) {
      int gn = n0 + wc * 64 + ni * 16 + (lane & 15);
      int r2 = gn - tensor * 384;
      int h = r2 >> 6, d = r2 & 63;
#pragma unroll
      for (int mi = 0; mi < 4; ++mi) {
        int gm0 = m0 + wr * 64 + mi * 16 + ((lane >> 4) << 2);
#pragma unroll
        for (int r = 0; r < 4; ++r) {
          int m = gm0 + r;
          int b = m >> 8, t = m & 255;
          kqv[(size_t)tensor * BHTD + ((((b * NHEAD + h) << 8) + t) << 6) + d] =
              f2bf(acc[mi][ni][r]);
        }
      }
    }
  }
}

// ---------------- causal flash attention, S[t,s] = Ksc[t]·Q[s] ----
// 128 t-rows per block, 8 waves x 16 rows, KV double-buffered, V pre-transposed.
// Counted-vmcnt double-barrier s-loop.
__global__ __launch_bounds__(512, 4) void attn_kernel(const u16* __restrict__ kqv,
                                                      u16* __restrict__ attnb) {
  __shared__ __align__(16) u16 lK[128 * 64];
  __shared__ __align__(16) u16 lQ[2][64 * 64];
  __shared__ __align__(16) u16 lVt[2][64 * 64];
  __shared__ __align__(16) char lP[8 * 16 * 144];
  const int tid = threadIdx.x;
  const int lane = tid & 63, w = tid >> 6;
  int bid = blockIdx.x;                       // 3072 = 8 * 384
  int id = (bid & 7) * 384 + (bid >> 3);
  const int bh = id >> 1, tt = id & 1;
  const int t0 = tt * 128;
  const u16* Kb = kqv + (size_t)bh * (T_SZ * DHEAD);
  const u16* Qb = kqv + (size_t)BHTD + (size_t)bh * (T_SZ * DHEAD);
  const u16* Vb = kqv + 2 * (size_t)BHTD + (size_t)bh * (DHEAD * T_SZ);  // [d][t]

#define STAGE_Q(buf, ss) { int ub = w * 64; int u = ub + lane; \
    int row = u >> 3, cu = u & 7; \
    gload_lds16(Qb + (size_t)((ss) + row) * DHEAD + ((cu ^ (row & 7)) << 3), lQ[buf] + ub * 8); }
#define STAGE_V(buf, ss) { int ub = w * 64; int u = ub + lane; \
    int row = u >> 3, cu = u & 7; \
    gload_lds16(Vb + (size_t)row * T_SZ + (ss) + ((cu ^ (row & 7)) << 3), lVt[buf] + ub * 8); }

  // prologue: K tile (128 rows) first, then Q0/V0 (stay in flight past vmcnt(2))
#pragma unroll
  for (int it = 0; it < 2; ++it) {
    int ub = it * 512 + w * 64;
    int u = ub + lane;
    int row = u >> 3, cu = u & 7;
    gload_lds16(Kb + (size_t)(t0 + row) * DHEAD + ((cu ^ (row & 7)) << 3), lK + ub * 8);
  }
  STAGE_Q(0, 0);
  STAGE_V(0, 0);
  asm volatile("s_waitcnt vmcnt(2)" ::: "memory");   // K's 2 loads landed
  asm volatile("s_barrier" ::: "memory");

  const int t0w = t0 + w * 16;                // wave's min t-row
  const int tg0 = t0w + ((lane >> 4) << 2);   // lane's first t-row
  bf16x8 af[2];
  {
    int arow = w * 16 + (lane & 15);
#pragma unroll
    for (int kk = 0; kk < 2; ++kk) {
      int cu = kk * 4 + (lane >> 4);
      af[kk] = *(const bf16x8*)((const char*)lK + arow * 128 + ((cu ^ (arow & 7)) << 4));
    }
  }
  char* lPw = lP + w * (16 * 144);
  f32x4 oacc[4] = {};
  float mrow[4] = {-1e30f, -1e30f, -1e30f, -1e30f};
  float lrowp[4] = {0.f, 0.f, 0.f, 0.f};
  const int nst = 2 * tt + 2;
  int cur = 0;
  for (int si = 0; si < nst; ++si) {
    const int s0 = si << 6;
    if (si + 1 < nst) {
      STAGE_Q(cur ^ 1, s0 + 64);
      STAGE_V(cur ^ 1, s0 + 64);
      asm volatile("s_waitcnt vmcnt(2)" ::: "memory");  // cur's Q,V landed
    } else {
      asm volatile("s_waitcnt vmcnt(0)" ::: "memory");
    }
    asm volatile("s_barrier" ::: "memory");
    if (s0 <= t0w + 15) {                     // wave has unmasked rows in this tile
      f32x4 sacc[4] = {};
#pragma unroll
      for (int ni = 0; ni < 4; ++ni) {
        int row = ni * 16 + (lane & 15);
#pragma unroll
        for (int kk = 0; kk < 2; ++kk) {
          int cu = kk * 4 + (lane >> 4);
          bf16x8 bq = *(const bf16x8*)((const char*)lQ[cur] + row * 128 + ((cu ^ (row & 7)) << 4));
          sacc[ni] = __builtin_amdgcn_mfma_f32_16x16x32_bf16(af[kk], bq, sacc[ni], 0, 0, 0);
        }
      }
      float pm[4][4];
      float rmax[4] = {-1e30f, -1e30f, -1e30f, -1e30f};
      if (s0 + 63 > t0w) {                    // diagonal tile: apply causal mask
#pragma unroll
        for (int ni = 0; ni < 4; ++ni) {
          int sg = s0 + ni * 16 + (lane & 15);
#pragma unroll
          for (int r = 0; r < 4; ++r) {
            float vv = sacc[ni][r];
            if (sg > tg0 + r) vv = -1e30f;
            pm[ni][r] = vv;
            rmax[r] = fmaxf(rmax[r], vv);
          }
        }
      } else {
#pragma unroll
        for (int ni = 0; ni < 4; ++ni)
#pragma unroll
          for (int r = 0; r < 4; ++r) {
            float vv = sacc[ni][r];
            pm[ni][r] = vv;
            rmax[r] = fmaxf(rmax[r], vv);
          }
      }
#pragma unroll
      for (int r = 0; r < 4; ++r) {
#pragma unroll
        for (int off = 1; off < 16; off <<= 1)
          rmax[r] = fmaxf(rmax[r], __shfl_xor(rmax[r], off));
      }
      // defer-max (T13): skip rescale when max growth <= 8
      bool small = (rmax[0] - mrow[0] <= 8.f) && (rmax[1] - mrow[1] <= 8.f) &&
                   (rmax[2] - mrow[2] <= 8.f) && (rmax[3] - mrow[3] <= 8.f);
      if (!__all(small)) {
#pragma unroll
        for (int r = 0; r < 4; ++r) {
          float mnew = fmaxf(mrow[r], rmax[r]);
          float alpha = __expf(mrow[r] - mnew);
          mrow[r] = mnew;
          lrowp[r] *= alpha;
#pragma unroll
          for (int nd = 0; nd < 4; ++nd) oacc[nd][r] *= alpha;
        }
      }
#pragma unroll
      for (int ni = 0; ni < 4; ++ni)
#pragma unroll
        for (int r = 0; r < 4; ++r) {
          float p = __expf(pm[ni][r] - mrow[r]);
          pm[ni][r] = p;
          lrowp[r] += p;                       // per-lane partial row-sum
        }
      // P -> per-wave LDS (stride 144: aligned 16B reads, bank-spread)
#pragma unroll
      for (int ni = 0; ni < 4; ++ni) {
        int scol = ni * 16 + (lane & 15);
#pragma unroll
        for (int r = 0; r < 4; ++r) {
          int trow = ((lane >> 4) << 2) + r;
          *(u16*)(lPw + trow * 144 + scol * 2) = f2bf(pm[ni][r]);
        }
      }
      bf16x8 pa[2];
      {
        int trow = lane & 15;
#pragma unroll
        for (int kk = 0; kk < 2; ++kk) {
          int cu = kk * 4 + (lane >> 4);
          pa[kk] = *(const bf16x8*)(lPw + trow * 144 + cu * 16);
        }
      }
#pragma unroll
      for (int nd = 0; nd < 4; ++nd) {
        int drow = nd * 16 + (lane & 15);
#pragma unroll
        for (int kk = 0; kk < 2; ++kk) {
          int cu = kk * 4 + (lane >> 4);
          bf16x8 vb = *(const bf16x8*)((const char*)lVt[cur] + drow * 128 + ((cu ^ (drow & 7)) << 4));
          oacc[nd] = __builtin_amdgcn_mfma_f32_16x16x32_bf16(pa[kk], vb, oacc[nd], 0, 0, 0);
        }
      }
    }
    asm volatile("s_barrier" ::: "memory");
    cur ^= 1;
  }
#undef STAGE_Q
#undef STAGE_V
  // final cross-lane row-sum reduce (once, not per tile)
#pragma unroll
  for (int r = 0; r < 4; ++r) {
#pragma unroll
    for (int off = 1; off < 16; off <<= 1)
      lrowp[r] += __shfl_xor(lrowp[r], off);
  }
  const int b = bh / NHEAD, h = bh - (bh / NHEAD) * NHEAD;
#pragma unroll
  for (int r = 0; r < 4; ++r) {
    int t = tg0 + r;
    float inv = 1.0f / lrowp[r];
#pragma unroll
    for (int nd = 0; nd < 4; ++nd) {
      int col = h * 64 + nd * 16 + (lane & 15);
      attnb[((size_t)(b * T_SZ + t)) * C_EMB + col] = f2bf(oacc[nd][r] * inv);
    }
  }
}

// ---------------- out projection: [65536,384] x [384,384] + bias -> fp32 ----
__global__ __launch_bounds__(256) void out_gemm(const u16* __restrict__ a,
                                                const u16* __restrict__ wt,
                                                const float* __restrict__ bias,
                                                float* __restrict__ out) {
  __shared__ __align__(16) u16 lA[2][128 * 64];
  __shared__ __align__(16) u16 lB[2][128 * 64];
  const int tid = threadIdx.x;
  const int lane = tid & 63, w = tid >> 6;
  int bid = blockIdx.x;
  int nb = (bid & 7) * 192 + (bid >> 3);
  int mt = nb / 3, nt = nb - mt * 3;
  const int n0 = nt * 128, m0 = mt * 128;
  const int wr = w >> 1, wc = w & 1;
  f32x4 acc[4][4] = {};

#define OSTAGE(buf, kt_) { \
    int k0_ = (kt_) * 64; \
    _Pragma("unroll") for (int it = 0; it < 4; ++it) { \
      int ub = it * 256 + w * 64; int u = ub + lane; \
      int row = u >> 3, cu = u & 7; \
      int koff = k0_ + ((cu ^ (row & 7)) << 3); \
      gload_lds16(a + (size_t)(m0 + row) * C_EMB + koff, lA[buf] + ub * 8); \
      gload_lds16(wt + (size_t)(n0 + row) * C_EMB + koff, lB[buf] + ub * 8); \
    } }

  OSTAGE(0, 0);
  int cur = 0;
  for (int kt = 0; kt < 6; ++kt) {
    if (kt < 5) {
      OSTAGE(cur ^ 1, kt + 1);
      asm volatile("s_waitcnt vmcnt(8)" ::: "memory");
    } else {
      asm volatile("s_waitcnt vmcnt(0)" ::: "memory");
    }
    asm volatile("s_barrier" ::: "memory");
    bf16x8 af[4][2], bfr[4][2];
#pragma unroll
    for (int mi = 0; mi < 4; ++mi) {
      int row = wr * 64 + mi * 16 + (lane & 15);
#pragma unroll
      for (int kk = 0; kk < 2; ++kk) {
        int cu = kk * 4 + (lane >> 4);
        af[mi][kk] = *(const bf16x8*)((const char*)lA[cur] + row * 128 + ((cu ^ (row & 7)) << 4));
      }
    }
#pragma unroll
    for (int ni = 0; ni < 4; ++ni) {
      int row = wc * 64 + ni * 16 + (lane & 15);
#pragma unroll
      for (int kk = 0; kk < 2; ++kk) {
        int cu = kk * 4 + (lane >> 4);
        bfr[ni][kk] = *(const bf16x8*)((const char*)lB[cur] + row * 128 + ((cu ^ (row & 7)) << 4));
      }
    }
#pragma unroll
    for (int kk = 0; kk < 2; ++kk)
#pragma unroll
      for (int mi = 0; mi < 4; ++mi)
#pragma unroll
        for (int ni = 0; ni < 4; ++ni)
          acc[mi][ni] = __builtin_amdgcn_mfma_f32_16x16x32_bf16(
              af[mi][kk], bfr[ni][kk], acc[mi][ni], 0, 0, 0);
    asm volatile("s_barrier" ::: "memory");
    cur ^= 1;
  }
#undef OSTAGE
#pragma unroll
  for (int ni = 0; ni < 4; ++ni) {
    int gn = n0 + wc * 64 + ni * 16 + (lane & 15);
    float bv = bias[gn];
#pragma unroll
    for (int mi = 0; mi < 4; ++mi) {
      int gm0 = m0 + wr * 64 + mi * 16 + ((lane >> 4) << 2);
#pragma unroll
      for (int r = 0; r < 4; ++r)
        out[(size_t)(gm0 + r) * C_EMB + gn] = acc[mi][ni][r] + bv;
    }
  }
}

extern "C" void kernel_launch(void* const* d_in, const int* in_sizes, int n_in,
                              void* d_out, int out_size, void* d_ws, size_t ws_size,
                              hipStream_t stream) {
  const float* x = (const float*)d_in[0];
  const float* wk = (const float*)d_in[1];
  const float* wq = (const float*)d_in[2];
  const float* wv = (const float*)d_in[3];
  const float* wproj = (const float*)d_in[4];
  const float* bproj = (const float*)d_in[5];
  float* out = (float*)d_out;
  u16* ws = (u16*)d_ws;
  u16* kqv = ws;                               // 3 * BHTD bf16 (K,Q [bhtd]; V [bhdt])
  u16* attnb = ws + 3 * (size_t)BHTD;          // BHTD bf16 (attn out)
  u16* xb = attnb;                             // aliases attnb: xb dead before attn writes
  u16* wqkvt = attnb + (size_t)BHTD;           // 1152*384
  u16* wprojt = wqkvt + (size_t)N3 * C_EMB;    // 384*384
  prep_weights<<<2304, 256, 0, stream>>>(wk, wq, wv, wproj, wqkvt, wprojt);
  prep_x<<<12288, 256, 0, stream>>>(x, xb);
  qkv_gemm<<<4608, 256, 0, stream>>>(xb, wqkvt, kqv);
  attn_kernel<<<3072, 512, 0, stream>>>(kqv, attnb);
  out_gemm<<<1536, 256, 0, stream>>>(attnb, wprojt, bproj, out);
}